// Round 7
// baseline (140.198 us; speedup 1.0000x reference)
//
#include <hip/hip_runtime.h>
#include <math.h>

// Problem constants (fixed by setup_inputs)
#define Nn 32
#define Cc 128
#define Ss 4096
#define Kk 64
#define NCHUNK 32
#define SCHUNK (Ss / NCHUNK)   // 128 pixels per block
#define ST 64                  // pixels per subtile
#define NSUB (SCHUNK / ST)     // 2 subtiles per block
#define BLK 256

// LDS strides (u16 units unless noted). All fragment rows 16B-aligned.
#define XCS 72    // xC [c][s]  (s-contig)   128x72 u16
#define XTS 136   // xT [s][c]  (c-contig)    64x136 u16
#define AS  72    // aB [k][s]  (s-contig)    64x72 u16
#define RSS 68    // red [g][s] stride in floats (16B-aligned rows)

typedef __attribute__((ext_vector_type(8))) short short8;   // bf16x8 MFMA frag
typedef __attribute__((ext_vector_type(4))) float float4v;  // fp32x4 MFMA acc

__device__ __forceinline__ unsigned f2bf(float f) {
    unsigned u = __builtin_bit_cast(unsigned, f);
    return (u + 0x7fffu + ((u >> 16) & 1u)) >> 16;   // RNE f32->bf16
}
__device__ __forceinline__ unsigned pack2(float a, float b) {
    return f2bf(a) | (f2bf(b) << 16);
}

// Fused NetVLAD main. Wave w owns s-window 16w..16w+15 for GEMM1+softmax
// (all 64 k in-wave -> wave-local softmax, logits never leave registers),
// and k-window 16w..16w+15 for GEMM2 (V[16k][128c] persistent acc).
// __launch_bounds__(256,2): wfrag (64 regs) must stay resident — (256,3) in
// R5 evicted it (VGPR 84, 2x slower). R6 measured: 104 VGPR + wfrag in AGPR
// = 168 regs -> 3 waves/SIMD OK; LDS 49.66 KB -> 3 blocks/CU OK. R6 was
// grid-starved at 512 blocks (2/CU); NCHUNK=32 -> 1024 blocks (~3 resident).
// MFMA 16x16x32 bf16: A[m][k=quad*8+j], B[k=quad*8+j][n=m], D col=m row=4q+r.
__global__ __launch_bounds__(BLK, 2) void netvlad_main(
    const float* __restrict__ x,
    const float* __restrict__ conv_w,
    const float* __restrict__ conv_b,
    float* __restrict__ vlad,
    float* __restrict__ asum)
{
    __shared__ __align__(16) unsigned short xC[Cc * XCS];  // 18432 B raw-x bf16 [c][s]
    __shared__ __align__(16) unsigned short xT[ST * XTS];  // 17408 B raw-x bf16 [s][c]
    __shared__ __align__(16) unsigned short aB[Kk * AS];   //  9216 B a' bf16 [k][s]
    __shared__ __align__(16) float red[16 * RSS];          //  4352 B ssq partials [g][s]
    __shared__ float bias_lds[Kk];
    float* asumLDS = red;                                  // reuse at end (1 KB)

    const int t    = threadIdx.x;
    const int n    = blockIdx.y;
    const int w    = t >> 6;
    const int m    = t & 15;
    const int quad = (t >> 4) & 3;
    const int sw   = 16 * w + m;      // this lane's pixel (GEMM1/softmax)

    if (t < Kk) bias_lds[t] = conv_b[t];

    // ---- one-time: conv_w A-fragments for ALL 64 k (bf16, 64 regs) ----
    short8 wfrag[4][4];   // [ktile][kstep]
#pragma unroll
    for (int kt = 0; kt < 4; ++kt) {
        const float* wr_ = conv_w + (16 * kt + m) * Cc;
#pragma unroll
        for (int ks = 0; ks < 4; ++ks) {
            float4 wa = *(const float4*)(wr_ + 32 * ks + 8 * quad);
            float4 wb = *(const float4*)(wr_ + 32 * ks + 8 * quad + 4);
            union { short8 s8; unsigned u[4]; } W_;
            W_.u[0] = pack2(wa.x, wa.y);
            W_.u[1] = pack2(wa.z, wa.w);
            W_.u[2] = pack2(wb.x, wb.y);
            W_.u[3] = pack2(wb.z, wb.w);
            wfrag[kt][ks] = W_.s8;
        }
    }

    float4v acc[8];                   // VLAD acc: k=16w+4q+r, c=16nt+m
#pragma unroll
    for (int nt = 0; nt < 8; ++nt) acc[nt] = (float4v){0.f, 0.f, 0.f, 0.f};
    float asum_part[16];              // raw-a sums, k=16kt+4q+r, this lane's s
#pragma unroll
    for (int j = 0; j < 16; ++j) asum_part[j] = 0.f;

    const float* xn = x + (size_t)n * Cc * Ss;

#pragma unroll 1
    for (int sub = 0; sub < NSUB; ++sub) {
        const int s0 = blockIdx.x * SCHUNK + sub * ST;
        __syncthreads();  // prev GEMM2 reads of xC/aB done

        // ---- stage: fp32 load -> ssq partials + bf16 xC [c][s] ----
        {
            const int g  = t >> 4;
            const int sq = (t & 15) << 2;
            float sp0 = 0.f, sp1 = 0.f, sp2 = 0.f, sp3 = 0.f;
#pragma unroll
            for (int r = 0; r < 8; ++r) {
                int c = g + 16 * r;
                float4 v = *(const float4*)(xn + (size_t)c * Ss + s0 + sq);
                sp0 += v.x * v.x; sp1 += v.y * v.y;
                sp2 += v.z * v.z; sp3 += v.w * v.w;
                uint2 pk = make_uint2(pack2(v.x, v.y), pack2(v.z, v.w));
                *(uint2*)&xC[c * XCS + sq] = pk;
            }
            *(float4*)&red[g * RSS + sq] = make_float4(sp0, sp1, sp2, sp3);
        }
        __syncthreads();

        // ---- transpose xC -> xT (paired-s b32 reads, b128 writes) ----
#pragma unroll
        for (int pass = 0; pass < 2; ++pass) {
            int oct = (t >> 5) + 8 * pass;   // c-octet 0..15
            int sp2_ = t & 31;               // s-pair
            unsigned r_[8];
#pragma unroll
            for (int j = 0; j < 8; ++j)
                r_[j] = *(const unsigned*)&xC[(8 * oct + j) * XCS + 2 * sp2_];
            uint4 lo, hi;
            lo.x = (r_[0] & 0xffffu) | (r_[1] << 16);
            lo.y = (r_[2] & 0xffffu) | (r_[3] << 16);
            lo.z = (r_[4] & 0xffffu) | (r_[5] << 16);
            lo.w = (r_[6] & 0xffffu) | (r_[7] << 16);
            hi.x = (r_[0] >> 16) | (r_[1] & 0xffff0000u);
            hi.y = (r_[2] >> 16) | (r_[3] & 0xffff0000u);
            hi.z = (r_[4] >> 16) | (r_[5] & 0xffff0000u);
            hi.w = (r_[6] >> 16) | (r_[7] & 0xffff0000u);
            *(uint4*)&xT[(2 * sp2_ + 0) * XTS + 8 * oct] = lo;
            *(uint4*)&xT[(2 * sp2_ + 1) * XTS + 8 * oct] = hi;
        }

        // ---- invn for this lane's pixel (register-only result) ----
        float pr = red[(4 * quad + 0) * RSS + sw] + red[(4 * quad + 1) * RSS + sw]
                 + red[(4 * quad + 2) * RSS + sw] + red[(4 * quad + 3) * RSS + sw];
        pr += __shfl_xor(pr, 16);
        pr += __shfl_xor(pr, 32);
        float invn = 1.0f / fmaxf(sqrtf(pr), 1e-12f);
        __syncthreads();  // xT complete

        // ---- GEMM1: L[all 64 k][s=16w+m]; B shared across 4 k-tiles ----
        float4v Lr[4];
#pragma unroll
        for (int kt = 0; kt < 4; ++kt) Lr[kt] = (float4v){0.f, 0.f, 0.f, 0.f};
#pragma unroll
        for (int ks = 0; ks < 4; ++ks) {
            short8 b = *(const short8*)&xT[sw * XTS + 32 * ks + 8 * quad];
#pragma unroll
            for (int kt = 0; kt < 4; ++kt)
                Lr[kt] = __builtin_amdgcn_mfma_f32_16x16x32_bf16(wfrag[kt][ks], b, Lr[kt], 0, 0, 0);
        }

        // ---- wave-local softmax over 64 k for pixel sw ----
        {
            float lg[16];
#pragma unroll
            for (int kt = 0; kt < 4; ++kt) {
                lg[4 * kt + 0] = Lr[kt].x * invn + bias_lds[16 * kt + 4 * quad + 0];
                lg[4 * kt + 1] = Lr[kt].y * invn + bias_lds[16 * kt + 4 * quad + 1];
                lg[4 * kt + 2] = Lr[kt].z * invn + bias_lds[16 * kt + 4 * quad + 2];
                lg[4 * kt + 3] = Lr[kt].w * invn + bias_lds[16 * kt + 4 * quad + 3];
            }
            float mx = lg[0];
#pragma unroll
            for (int j = 1; j < 16; ++j) mx = fmaxf(mx, lg[j]);
            mx = fmaxf(mx, __shfl_xor(mx, 16));
            mx = fmaxf(mx, __shfl_xor(mx, 32));
            float lsum = 0.f;
#pragma unroll
            for (int j = 0; j < 16; ++j) { lg[j] = __expf(lg[j] - mx); lsum += lg[j]; }
            lsum += __shfl_xor(lsum, 16);
            lsum += __shfl_xor(lsum, 32);
            float itot = 1.0f / lsum;
            float sca  = itot * invn;    // fold invn into a' (GEMM2 x is raw)
#pragma unroll
            for (int j = 0; j < 16; ++j) asum_part[j] += lg[j] * itot;
#pragma unroll
            for (int kt = 0; kt < 4; ++kt) {
                aB[(16 * kt + 4 * quad + 0) * AS + sw] = (unsigned short)f2bf(lg[4 * kt + 0] * sca);
                aB[(16 * kt + 4 * quad + 1) * AS + sw] = (unsigned short)f2bf(lg[4 * kt + 1] * sca);
                aB[(16 * kt + 4 * quad + 2) * AS + sw] = (unsigned short)f2bf(lg[4 * kt + 2] * sca);
                aB[(16 * kt + 4 * quad + 3) * AS + sw] = (unsigned short)f2bf(lg[4 * kt + 3] * sca);
            }
        }
        __syncthreads();  // aB complete

        // ---- GEMM2: V[k=16w..][c] += a'[k][s] x X^T[s][c] ----
#pragma unroll
        for (int ks = 0; ks < 2; ++ks) {
            short8 af = *(const short8*)&aB[(16 * w + m) * AS + 32 * ks + 8 * quad];
#pragma unroll
            for (int nt = 0; nt < 8; ++nt) {
                short8 bf_ = *(const short8*)&xC[(16 * nt + m) * XCS + 32 * ks + 8 * quad];
                acc[nt] = __builtin_amdgcn_mfma_f32_16x16x32_bf16(af, bf_, acc[nt], 0, 0, 0);
            }
        }
    }

    // ---- commit vlad partials: lane holds D[k=16w+4q+r][c=16nt+m] ----
    float* vb = vlad + ((size_t)n * Kk + 16 * w + 4 * quad) * Cc + m;
#pragma unroll
    for (int nt = 0; nt < 8; ++nt) {
        atomicAdd(vb + 0 * Cc + 16 * nt, acc[nt].x);
        atomicAdd(vb + 1 * Cc + 16 * nt, acc[nt].y);
        atomicAdd(vb + 2 * Cc + 16 * nt, acc[nt].z);
        atomicAdd(vb + 3 * Cc + 16 * nt, acc[nt].w);
    }

    // ---- asum: in-wave reduce over s-lanes, then cross-wave via LDS ----
#pragma unroll
    for (int j = 0; j < 16; ++j) {
        float v = asum_part[j];
        v += __shfl_xor(v, 1);
        v += __shfl_xor(v, 2);
        v += __shfl_xor(v, 4);
        v += __shfl_xor(v, 8);
        asum_part[j] = v;
    }
    __syncthreads();  // red's last (invn) reads done; safe to alias
    if (m == 0) {
#pragma unroll
        for (int kt = 0; kt < 4; ++kt)
#pragma unroll
            for (int r = 0; r < 4; ++r)
                asumLDS[w * 64 + 16 * kt + 4 * quad + r] = asum_part[4 * kt + r];
    }
    __syncthreads();
    if (t < Kk) {
        float s_ = asumLDS[t] + asumLDS[64 + t] + asumLDS[128 + t] + asumLDS[192 + t];
        atomicAdd(&asum[n * Kk + t], s_);
    }
}

// Parallel finalize: one block per n. Phase 1: per-k intra-norm scale via
// 4-thread teams + LDS reduce. Phase 2: out[n][c] = sum_k scale*(vlad-as*cent).
__global__ __launch_bounds__(256) void netvlad_final(
    const float* __restrict__ vlad, const float* __restrict__ asum,
    const float* __restrict__ centroids, const float* __restrict__ fc_w,
    float* __restrict__ out)
{
    __shared__ float scale_s[Kk];
    __shared__ float asum_s[Kk];
    __shared__ float red2[Kk][4];

    const int n = blockIdx.x;
    const int t = threadIdx.x;
    const int k = t >> 2;
    const int q = t & 3;

    const float* vr = vlad + ((size_t)n * Kk + k) * Cc + q * 32;
    const float* cr = centroids + k * Cc + q * 32;
    const float  as = asum[n * Kk + k];

    float ssq = 0.f;
#pragma unroll
    for (int i = 0; i < 8; ++i) {
        float4 v4 = *(const float4*)(vr + 4 * i);
        float4 c4 = *(const float4*)(cr + 4 * i);
        float d0 = v4.x - as * c4.x;
        float d1 = v4.y - as * c4.y;
        float d2 = v4.z - as * c4.z;
        float d3 = v4.w - as * c4.w;
        ssq += d0 * d0 + d1 * d1 + d2 * d2 + d3 * d3;
    }
    red2[k][q] = ssq;
    __syncthreads();
    if (q == 0) {
        float tot = red2[k][0] + red2[k][1] + red2[k][2] + red2[k][3];
        scale_s[k] = fc_w[k] / fmaxf(sqrtf(tot), 1e-12f);
        asum_s[k]  = as;
    }
    __syncthreads();

    if (t < Cc) {
        const int c = t;
        const float* vbp = vlad + (size_t)n * Kk * Cc + c;
        float o = 0.f;
#pragma unroll 8
        for (int k2 = 0; k2 < Kk; ++k2)
            o += scale_s[k2] * (vbp[k2 * Cc] - asum_s[k2] * centroids[k2 * Cc + c]);
        out[n * Cc + c] = o;
    }
}

extern "C" void kernel_launch(void* const* d_in, const int* in_sizes, int n_in,
                              void* d_out, int out_size, void* d_ws, size_t ws_size,
                              hipStream_t stream) {
    (void)in_sizes; (void)n_in; (void)out_size; (void)ws_size;
    const float* x         = (const float*)d_in[0];
    const float* conv_w    = (const float*)d_in[1];
    const float* conv_b    = (const float*)d_in[2];
    const float* centroids = (const float*)d_in[3];
    const float* fc_w      = (const float*)d_in[4];
    float* out = (float*)d_out;

    float* vlad = (float*)d_ws;                         // [N][K][C] = 1 MB
    float* asum = vlad + (size_t)Nn * Kk * Cc;          // [N][K]    = 8 KB
    size_t zero_bytes = ((size_t)Nn * Kk * Cc + (size_t)Nn * Kk) * sizeof(float);
    hipMemsetAsync(d_ws, 0, zero_bytes, stream);        // ws is poisoned 0xAA each call

    dim3 grid(NCHUNK, Nn);
    netvlad_main<<<grid, BLK, 0, stream>>>(x, conv_w, conv_b, vlad, asum);
    netvlad_final<<<Nn, 256, 0, stream>>>(vlad, asum, centroids, fc_w, out);
}

// Round 8
// 129.058 us; speedup vs baseline: 1.0863x; 1.0863x over previous
//
#include <hip/hip_runtime.h>
#include <math.h>

// Problem constants (fixed by setup_inputs)
#define Nn 32
#define Cc 128
#define Ss 4096
#define Kk 64
#define NCHUNK 16
#define SCHUNK (Ss / NCHUNK)   // 256 pixels per block
#define ST 64                  // pixels per subtile
#define NSUB (SCHUNK / ST)     // 4 subtiles per block
#define BLK 256

// LDS strides (u16 units unless noted). All fragment rows 16B-aligned.
#define XCS 72    // xC [c][s]  (s-contig)   128x72 u16
#define XTS 136   // xT [s][c]  (c-contig)    64x136 u16
#define AS  72    // aB [k][s]  (s-contig)    64x72 u16
#define RSS 68    // red [g][s] stride in floats (16B-aligned rows)

typedef __attribute__((ext_vector_type(8))) short short8;   // bf16x8 MFMA frag
typedef __attribute__((ext_vector_type(4))) float float4v;  // fp32x4 MFMA acc

__device__ __forceinline__ unsigned f2bf(float f) {
    unsigned u = __builtin_bit_cast(unsigned, f);
    return (u + 0x7fffu + ((u >> 16) & 1u)) >> 16;   // RNE f32->bf16
}
__device__ __forceinline__ unsigned pack2(float a, float b) {
    return f2bf(a) | (f2bf(b) << 16);
}

// Fused NetVLAD main, software-pipelined staging, slab (non-atomic) commit.
// Register budget lesson (R5/R6/R7): wfrag=64 regs must stay resident;
// 104-108 VGPR + 64 AGPR = ~172 -> 2 waves/SIMD is the fixed residency;
// grid beyond 512 blocks buys nothing (R7). Prefetch regs are "free" up to
// 256 total. MFMA 16x16x32 bf16: A[m][k=q*8+j], B[k=q*8+j][n=m], D col=m row=4q+r.
__global__ __launch_bounds__(BLK, 2) void netvlad_main(
    const float* __restrict__ x,
    const float* __restrict__ conv_w,
    const float* __restrict__ conv_b,
    float* __restrict__ vlad_part,   // [NCHUNK][Nn][Kk][Cc]
    float* __restrict__ asum_part_g) // [NCHUNK][Nn][Kk]
{
    __shared__ __align__(16) unsigned short xC[Cc * XCS];  // 18432 B raw-x bf16 [c][s]
    __shared__ __align__(16) unsigned short xT[ST * XTS];  // 17408 B raw-x bf16 [s][c]
    __shared__ __align__(16) unsigned short aB[Kk * AS];   //  9216 B a' bf16 [k][s]
    __shared__ __align__(16) float red[16 * RSS];          //  4352 B ssq partials [g][s]
    __shared__ float bias_lds[Kk];
    float* asumLDS = red;                                  // reuse at end (1 KB)

    const int t    = threadIdx.x;
    const int n    = blockIdx.y;
    const int w    = t >> 6;
    const int m    = t & 15;
    const int quad = (t >> 4) & 3;
    const int sw   = 16 * w + m;      // this lane's pixel (GEMM1/softmax)

    if (t < Kk) bias_lds[t] = conv_b[t];

    // ---- one-time: conv_w A-fragments for ALL 64 k (bf16, 64 regs) ----
    short8 wfrag[4][4];   // [ktile][kstep]
#pragma unroll
    for (int kt = 0; kt < 4; ++kt) {
        const float* wr_ = conv_w + (16 * kt + m) * Cc;
#pragma unroll
        for (int ks = 0; ks < 4; ++ks) {
            float4 wa = *(const float4*)(wr_ + 32 * ks + 8 * quad);
            float4 wb = *(const float4*)(wr_ + 32 * ks + 8 * quad + 4);
            union { short8 s8; unsigned u[4]; } W_;
            W_.u[0] = pack2(wa.x, wa.y);
            W_.u[1] = pack2(wa.z, wa.w);
            W_.u[2] = pack2(wb.x, wb.y);
            W_.u[3] = pack2(wb.z, wb.w);
            wfrag[kt][ks] = W_.s8;
        }
    }

    float4v acc[8];                   // VLAD acc: k=16w+4q+r, c=16nt+m
#pragma unroll
    for (int nt = 0; nt < 8; ++nt) acc[nt] = (float4v){0.f, 0.f, 0.f, 0.f};
    float asum_part[16];              // raw-a sums, k=16kt+4q+r, this lane's s
#pragma unroll
    for (int j = 0; j < 16; ++j) asum_part[j] = 0.f;

    const float* xn  = x + (size_t)n * Cc * Ss;
    const int g      = t >> 4;
    const int sq     = (t & 15) << 2;
    const int sbase  = blockIdx.x * SCHUNK;

    // ---- prologue: prefetch subtile 0 into registers ----
    float4 pv[8];
#pragma unroll
    for (int r = 0; r < 8; ++r)
        pv[r] = *(const float4*)(xn + (size_t)(g + 16 * r) * Ss + sbase + sq);

#pragma unroll 1
    for (int sub = 0; sub < NSUB; ++sub) {
        __syncthreads();  // prev GEMM2 reads of xC/aB done

        // ---- stage from prefetch regs: ssq partials + bf16 xC [c][s] ----
        {
            float sp0 = 0.f, sp1 = 0.f, sp2 = 0.f, sp3 = 0.f;
#pragma unroll
            for (int r = 0; r < 8; ++r) {
                float4 v = pv[r];
                sp0 += v.x * v.x; sp1 += v.y * v.y;
                sp2 += v.z * v.z; sp3 += v.w * v.w;
                uint2 pk = make_uint2(pack2(v.x, v.y), pack2(v.z, v.w));
                *(uint2*)&xC[(g + 16 * r) * XCS + sq] = pk;
            }
            *(float4*)&red[g * RSS + sq] = make_float4(sp0, sp1, sp2, sp3);
        }
        // ---- issue next subtile's loads (overlap with all compute below) ----
        if (sub + 1 < NSUB) {
            const int s0n = sbase + (sub + 1) * ST;
#pragma unroll
            for (int r = 0; r < 8; ++r)
                pv[r] = *(const float4*)(xn + (size_t)(g + 16 * r) * Ss + s0n + sq);
        }
        __syncthreads();

        // ---- transpose xC -> xT (paired-s b32 reads, b128 writes) ----
#pragma unroll
        for (int pass = 0; pass < 2; ++pass) {
            int oct = (t >> 5) + 8 * pass;   // c-octet 0..15
            int sp2_ = t & 31;               // s-pair
            unsigned r_[8];
#pragma unroll
            for (int j = 0; j < 8; ++j)
                r_[j] = *(const unsigned*)&xC[(8 * oct + j) * XCS + 2 * sp2_];
            uint4 lo, hi;
            lo.x = (r_[0] & 0xffffu) | (r_[1] << 16);
            lo.y = (r_[2] & 0xffffu) | (r_[3] << 16);
            lo.z = (r_[4] & 0xffffu) | (r_[5] << 16);
            lo.w = (r_[6] & 0xffffu) | (r_[7] << 16);
            hi.x = (r_[0] >> 16) | (r_[1] & 0xffff0000u);
            hi.y = (r_[2] >> 16) | (r_[3] & 0xffff0000u);
            hi.z = (r_[4] >> 16) | (r_[5] & 0xffff0000u);
            hi.w = (r_[6] >> 16) | (r_[7] & 0xffff0000u);
            *(uint4*)&xT[(2 * sp2_ + 0) * XTS + 8 * oct] = lo;
            *(uint4*)&xT[(2 * sp2_ + 1) * XTS + 8 * oct] = hi;
        }

        // ---- invn for this lane's pixel (register-only result) ----
        float pr = red[(4 * quad + 0) * RSS + sw] + red[(4 * quad + 1) * RSS + sw]
                 + red[(4 * quad + 2) * RSS + sw] + red[(4 * quad + 3) * RSS + sw];
        pr += __shfl_xor(pr, 16);
        pr += __shfl_xor(pr, 32);
        float invn = 1.0f / fmaxf(sqrtf(pr), 1e-12f);
        __syncthreads();  // xT complete

        // ---- GEMM1: L[all 64 k][s=16w+m]; B shared across 4 k-tiles ----
        float4v Lr[4];
#pragma unroll
        for (int kt = 0; kt < 4; ++kt) Lr[kt] = (float4v){0.f, 0.f, 0.f, 0.f};
#pragma unroll
        for (int ks = 0; ks < 4; ++ks) {
            short8 b = *(const short8*)&xT[sw * XTS + 32 * ks + 8 * quad];
#pragma unroll
            for (int kt = 0; kt < 4; ++kt)
                Lr[kt] = __builtin_amdgcn_mfma_f32_16x16x32_bf16(wfrag[kt][ks], b, Lr[kt], 0, 0, 0);
        }

        // ---- wave-local softmax over 64 k for pixel sw ----
        {
            float lg[16];
#pragma unroll
            for (int kt = 0; kt < 4; ++kt) {
                lg[4 * kt + 0] = Lr[kt].x * invn + bias_lds[16 * kt + 4 * quad + 0];
                lg[4 * kt + 1] = Lr[kt].y * invn + bias_lds[16 * kt + 4 * quad + 1];
                lg[4 * kt + 2] = Lr[kt].z * invn + bias_lds[16 * kt + 4 * quad + 2];
                lg[4 * kt + 3] = Lr[kt].w * invn + bias_lds[16 * kt + 4 * quad + 3];
            }
            float mx = lg[0];
#pragma unroll
            for (int j = 1; j < 16; ++j) mx = fmaxf(mx, lg[j]);
            mx = fmaxf(mx, __shfl_xor(mx, 16));
            mx = fmaxf(mx, __shfl_xor(mx, 32));
            float lsum = 0.f;
#pragma unroll
            for (int j = 0; j < 16; ++j) { lg[j] = __expf(lg[j] - mx); lsum += lg[j]; }
            lsum += __shfl_xor(lsum, 16);
            lsum += __shfl_xor(lsum, 32);
            float itot = 1.0f / lsum;
            float sca  = itot * invn;    // fold invn into a' (GEMM2 x is raw)
#pragma unroll
            for (int j = 0; j < 16; ++j) asum_part[j] += lg[j] * itot;
#pragma unroll
            for (int kt = 0; kt < 4; ++kt) {
                aB[(16 * kt + 4 * quad + 0) * AS + sw] = (unsigned short)f2bf(lg[4 * kt + 0] * sca);
                aB[(16 * kt + 4 * quad + 1) * AS + sw] = (unsigned short)f2bf(lg[4 * kt + 1] * sca);
                aB[(16 * kt + 4 * quad + 2) * AS + sw] = (unsigned short)f2bf(lg[4 * kt + 2] * sca);
                aB[(16 * kt + 4 * quad + 3) * AS + sw] = (unsigned short)f2bf(lg[4 * kt + 3] * sca);
            }
        }
        __syncthreads();  // aB complete

        // ---- GEMM2: V[k=16w..][c] += a'[k][s] x X^T[s][c] ----
#pragma unroll
        for (int ks = 0; ks < 2; ++ks) {
            short8 af = *(const short8*)&aB[(16 * w + m) * AS + 32 * ks + 8 * quad];
#pragma unroll
            for (int nt = 0; nt < 8; ++nt) {
                short8 bf_ = *(const short8*)&xC[(16 * nt + m) * XCS + 32 * ks + 8 * quad];
                acc[nt] = __builtin_amdgcn_mfma_f32_16x16x32_bf16(af, bf_, acc[nt], 0, 0, 0);
            }
        }
    }

    // ---- commit vlad slab (plain stores; slab fully written, no init) ----
    float* vb = vlad_part + (((size_t)blockIdx.x * Nn + n) * Kk + 16 * w + 4 * quad) * Cc + m;
#pragma unroll
    for (int nt = 0; nt < 8; ++nt) {
        vb[0 * Cc + 16 * nt] = acc[nt].x;
        vb[1 * Cc + 16 * nt] = acc[nt].y;
        vb[2 * Cc + 16 * nt] = acc[nt].z;
        vb[3 * Cc + 16 * nt] = acc[nt].w;
    }

    // ---- asum: in-wave reduce over s-lanes, cross-wave via LDS, slab store ----
#pragma unroll
    for (int j = 0; j < 16; ++j) {
        float v = asum_part[j];
        v += __shfl_xor(v, 1);
        v += __shfl_xor(v, 2);
        v += __shfl_xor(v, 4);
        v += __shfl_xor(v, 8);
        asum_part[j] = v;
    }
    __syncthreads();  // red's last (invn) reads done; safe to alias
    if (m == 0) {
#pragma unroll
        for (int kt = 0; kt < 4; ++kt)
#pragma unroll
            for (int r = 0; r < 4; ++r)
                asumLDS[w * 64 + 16 * kt + 4 * quad + r] = asum_part[4 * kt + r];
    }
    __syncthreads();
    if (t < Kk) {
        float s_ = asumLDS[t] + asumLDS[64 + t] + asumLDS[128 + t] + asumLDS[192 + t];
        asum_part_g[((size_t)blockIdx.x * Nn + n) * Kk + t] = s_;
    }
}

// Finalize: one block per n. Reduce 16 slabs -> vred (LDS), intra-normalize,
// FC. Phase 0: asum slab-reduce. Phase 1: vlad slab-reduce + centroid subtract
// + ssq. Phase 2: out[n][c] = sum_k scale*vred[k][c].
__global__ __launch_bounds__(256) void netvlad_final(
    const float* __restrict__ vlad_part, const float* __restrict__ asum_part_g,
    const float* __restrict__ centroids, const float* __restrict__ fc_w,
    float* __restrict__ out)
{
    __shared__ __align__(16) float vred[Kk * Cc];   // 32 KB: d = vlad - as*cent
    __shared__ float scale_s[Kk];
    __shared__ float asum_s[Kk];
    __shared__ float red2[Kk][4];

    const int n = blockIdx.x;
    const int t = threadIdx.x;
    const int k = t >> 2;
    const int q = t & 3;

    if (t < Kk) {
        float s_ = 0.f;
#pragma unroll
        for (int ch = 0; ch < NCHUNK; ++ch)
            s_ += asum_part_g[((size_t)ch * Nn + n) * Kk + t];
        asum_s[t] = s_;
    }

    float4 v[8];
#pragma unroll
    for (int i = 0; i < 8; ++i) v[i] = make_float4(0.f, 0.f, 0.f, 0.f);
#pragma unroll 2
    for (int ch = 0; ch < NCHUNK; ++ch) {
        const float* base = vlad_part + (((size_t)ch * Nn + n) * Kk + k) * Cc + q * 32;
#pragma unroll
        for (int i = 0; i < 8; ++i) {
            float4 u = *(const float4*)(base + 4 * i);
            v[i].x += u.x; v[i].y += u.y; v[i].z += u.z; v[i].w += u.w;
        }
    }
    __syncthreads();   // asum_s ready
    const float as = asum_s[k];
    const float* cr = centroids + k * Cc + q * 32;
    float ssq = 0.f;
#pragma unroll
    for (int i = 0; i < 8; ++i) {
        float4 c4 = *(const float4*)(cr + 4 * i);
        float4 d;
        d.x = v[i].x - as * c4.x;
        d.y = v[i].y - as * c4.y;
        d.z = v[i].z - as * c4.z;
        d.w = v[i].w - as * c4.w;
        ssq += d.x * d.x + d.y * d.y + d.z * d.z + d.w * d.w;
        *(float4*)&vred[k * Cc + q * 32 + 4 * i] = d;
    }
    red2[k][q] = ssq;
    __syncthreads();
    if (q == 0) {
        float tot = red2[k][0] + red2[k][1] + red2[k][2] + red2[k][3];
        scale_s[k] = fc_w[k] / fmaxf(sqrtf(tot), 1e-12f);
    }
    __syncthreads();

    if (t < Cc) {
        float o = 0.f;
#pragma unroll 8
        for (int k2 = 0; k2 < Kk; ++k2)
            o += scale_s[k2] * vred[k2 * Cc + t];
        out[n * Cc + t] = o;
    }
}

extern "C" void kernel_launch(void* const* d_in, const int* in_sizes, int n_in,
                              void* d_out, int out_size, void* d_ws, size_t ws_size,
                              hipStream_t stream) {
    (void)in_sizes; (void)n_in; (void)out_size; (void)ws_size;
    const float* x         = (const float*)d_in[0];
    const float* conv_w    = (const float*)d_in[1];
    const float* conv_b    = (const float*)d_in[2];
    const float* centroids = (const float*)d_in[3];
    const float* fc_w      = (const float*)d_in[4];
    float* out = (float*)d_out;

    // ws layout: vlad_part [NCHUNK][Nn][Kk][Cc] (16.8 MB) + asum_part [NCHUNK][Nn][Kk]
    // (512 KB). Both fully written by netvlad_main -> no zero-init needed.
    float* vlad_part = (float*)d_ws;
    float* asum_part = vlad_part + (size_t)NCHUNK * Nn * Kk * Cc;

    dim3 grid(NCHUNK, Nn);
    netvlad_main<<<grid, BLK, 0, stream>>>(x, conv_w, conv_b, vlad_part, asum_part);
    netvlad_final<<<Nn, 256, 0, stream>>>(vlad_part, asum_part, centroids, fc_w, out);
}

// Round 9
// 124.028 us; speedup vs baseline: 1.1304x; 1.0406x over previous
//
#include <hip/hip_runtime.h>
#include <math.h>

// Problem constants (fixed by setup_inputs)
#define Nn 32
#define Cc 128
#define Ss 4096
#define Kk 64
#define NCHUNK 16
#define SCHUNK (Ss / NCHUNK)   // 256 pixels per block
#define ST 64                  // pixels per subtile
#define NSUB (SCHUNK / ST)     // 4 subtiles per block
#define BLK 256

// LDS strides (u16 units unless noted). All fragment rows 16B-aligned.
#define XCS 72    // xC [c][s]  (s-contig)   128x72 u16
#define XTS 136   // xT [s][c]  (c-contig)    64x136 u16
#define AS  72    // aB [k][s]  (s-contig)    64x72 u16
#define RSS 68    // red [g][s] stride in floats (16B-aligned rows)

typedef __attribute__((ext_vector_type(8))) short short8;   // bf16x8 MFMA frag
typedef __attribute__((ext_vector_type(4))) float float4v;  // fp32x4 MFMA acc

__device__ __forceinline__ unsigned f2bf(float f) {
    unsigned u = __builtin_bit_cast(unsigned, f);
    return (u + 0x7fffu + ((u >> 16) & 1u)) >> 16;   // RNE f32->bf16
}
__device__ __forceinline__ unsigned pack2(float a, float b) {
    return f2bf(a) | (f2bf(b) << 16);
}

// Fused NetVLAD main, software-pipelined staging (R8), atomic compact commit
// (R4 — slab commit in R8 cost +13us in the 32-block finalize re-read).
// Register lessons (R5-R7): wfrag=64 regs must stay resident; ~172 regs ->
// 2 waves/SIMD fixed; grid beyond 512 buys nothing. Prefetch regs are free.
// MFMA 16x16x32 bf16: A[m][k=q*8+j], B[k=q*8+j][n=m], D col=m row=4q+r.
__global__ __launch_bounds__(BLK, 2) void netvlad_main(
    const float* __restrict__ x,
    const float* __restrict__ conv_w,
    const float* __restrict__ conv_b,
    float* __restrict__ vlad,
    float* __restrict__ asum)
{
    __shared__ __align__(16) unsigned short xC[Cc * XCS];  // 18432 B raw-x bf16 [c][s]
    __shared__ __align__(16) unsigned short xT[ST * XTS];  // 17408 B raw-x bf16 [s][c]
    __shared__ __align__(16) unsigned short aB[Kk * AS];   //  9216 B a' bf16 [k][s]
    __shared__ __align__(16) float red[16 * RSS];          //  4352 B ssq partials [g][s]
    __shared__ float bias_lds[Kk];
    float* asumLDS = red;                                  // reuse at end (1 KB)

    const int t    = threadIdx.x;
    const int n    = blockIdx.y;
    const int w    = t >> 6;
    const int m    = t & 15;
    const int quad = (t >> 4) & 3;
    const int sw   = 16 * w + m;      // this lane's pixel (GEMM1/softmax)

    if (t < Kk) bias_lds[t] = conv_b[t];

    // ---- one-time: conv_w A-fragments for ALL 64 k (bf16, 64 regs) ----
    short8 wfrag[4][4];   // [ktile][kstep]
#pragma unroll
    for (int kt = 0; kt < 4; ++kt) {
        const float* wr_ = conv_w + (16 * kt + m) * Cc;
#pragma unroll
        for (int ks = 0; ks < 4; ++ks) {
            float4 wa = *(const float4*)(wr_ + 32 * ks + 8 * quad);
            float4 wb = *(const float4*)(wr_ + 32 * ks + 8 * quad + 4);
            union { short8 s8; unsigned u[4]; } W_;
            W_.u[0] = pack2(wa.x, wa.y);
            W_.u[1] = pack2(wa.z, wa.w);
            W_.u[2] = pack2(wb.x, wb.y);
            W_.u[3] = pack2(wb.z, wb.w);
            wfrag[kt][ks] = W_.s8;
        }
    }

    float4v acc[8];                   // VLAD acc: k=16w+4q+r, c=16nt+m
#pragma unroll
    for (int nt = 0; nt < 8; ++nt) acc[nt] = (float4v){0.f, 0.f, 0.f, 0.f};
    float asum_part[16];              // raw-a sums, k=16kt+4q+r, this lane's s
#pragma unroll
    for (int j = 0; j < 16; ++j) asum_part[j] = 0.f;

    const float* xn  = x + (size_t)n * Cc * Ss;
    const int g      = t >> 4;
    const int sq     = (t & 15) << 2;
    const int sbase  = blockIdx.x * SCHUNK;

    // ---- prologue: prefetch subtile 0 into registers ----
    float4 pv[8];
#pragma unroll
    for (int r = 0; r < 8; ++r)
        pv[r] = *(const float4*)(xn + (size_t)(g + 16 * r) * Ss + sbase + sq);

#pragma unroll 1
    for (int sub = 0; sub < NSUB; ++sub) {
        __syncthreads();  // prev GEMM2 reads of xC/aB done

        // ---- stage from prefetch regs: ssq partials + bf16 xC [c][s] ----
        {
            float sp0 = 0.f, sp1 = 0.f, sp2 = 0.f, sp3 = 0.f;
#pragma unroll
            for (int r = 0; r < 8; ++r) {
                float4 v = pv[r];
                sp0 += v.x * v.x; sp1 += v.y * v.y;
                sp2 += v.z * v.z; sp3 += v.w * v.w;
                uint2 pk = make_uint2(pack2(v.x, v.y), pack2(v.z, v.w));
                *(uint2*)&xC[(g + 16 * r) * XCS + sq] = pk;
            }
            *(float4*)&red[g * RSS + sq] = make_float4(sp0, sp1, sp2, sp3);
        }
        // ---- issue next subtile's loads (overlap with all compute below) ----
        if (sub + 1 < NSUB) {
            const int s0n = sbase + (sub + 1) * ST;
#pragma unroll
            for (int r = 0; r < 8; ++r)
                pv[r] = *(const float4*)(xn + (size_t)(g + 16 * r) * Ss + s0n + sq);
        }
        __syncthreads();

        // ---- transpose xC -> xT (paired-s b32 reads, b128 writes) ----
#pragma unroll
        for (int pass = 0; pass < 2; ++pass) {
            int oct = (t >> 5) + 8 * pass;   // c-octet 0..15
            int sp2_ = t & 31;               // s-pair
            unsigned r_[8];
#pragma unroll
            for (int j = 0; j < 8; ++j)
                r_[j] = *(const unsigned*)&xC[(8 * oct + j) * XCS + 2 * sp2_];
            uint4 lo, hi;
            lo.x = (r_[0] & 0xffffu) | (r_[1] << 16);
            lo.y = (r_[2] & 0xffffu) | (r_[3] << 16);
            lo.z = (r_[4] & 0xffffu) | (r_[5] << 16);
            lo.w = (r_[6] & 0xffffu) | (r_[7] << 16);
            hi.x = (r_[0] >> 16) | (r_[1] & 0xffff0000u);
            hi.y = (r_[2] >> 16) | (r_[3] & 0xffff0000u);
            hi.z = (r_[4] >> 16) | (r_[5] & 0xffff0000u);
            hi.w = (r_[6] >> 16) | (r_[7] & 0xffff0000u);
            *(uint4*)&xT[(2 * sp2_ + 0) * XTS + 8 * oct] = lo;
            *(uint4*)&xT[(2 * sp2_ + 1) * XTS + 8 * oct] = hi;
        }

        // ---- invn for this lane's pixel (register-only result) ----
        float pr = red[(4 * quad + 0) * RSS + sw] + red[(4 * quad + 1) * RSS + sw]
                 + red[(4 * quad + 2) * RSS + sw] + red[(4 * quad + 3) * RSS + sw];
        pr += __shfl_xor(pr, 16);
        pr += __shfl_xor(pr, 32);
        float invn = 1.0f / fmaxf(sqrtf(pr), 1e-12f);
        __syncthreads();  // xT complete

        // ---- GEMM1: L[all 64 k][s=16w+m]; B shared across 4 k-tiles ----
        float4v Lr[4];
#pragma unroll
        for (int kt = 0; kt < 4; ++kt) Lr[kt] = (float4v){0.f, 0.f, 0.f, 0.f};
#pragma unroll
        for (int ks = 0; ks < 4; ++ks) {
            short8 b = *(const short8*)&xT[sw * XTS + 32 * ks + 8 * quad];
#pragma unroll
            for (int kt = 0; kt < 4; ++kt)
                Lr[kt] = __builtin_amdgcn_mfma_f32_16x16x32_bf16(wfrag[kt][ks], b, Lr[kt], 0, 0, 0);
        }

        // ---- wave-local softmax over 64 k for pixel sw ----
        {
            float lg[16];
#pragma unroll
            for (int kt = 0; kt < 4; ++kt) {
                lg[4 * kt + 0] = Lr[kt].x * invn + bias_lds[16 * kt + 4 * quad + 0];
                lg[4 * kt + 1] = Lr[kt].y * invn + bias_lds[16 * kt + 4 * quad + 1];
                lg[4 * kt + 2] = Lr[kt].z * invn + bias_lds[16 * kt + 4 * quad + 2];
                lg[4 * kt + 3] = Lr[kt].w * invn + bias_lds[16 * kt + 4 * quad + 3];
            }
            float mx = lg[0];
#pragma unroll
            for (int j = 1; j < 16; ++j) mx = fmaxf(mx, lg[j]);
            mx = fmaxf(mx, __shfl_xor(mx, 16));
            mx = fmaxf(mx, __shfl_xor(mx, 32));
            float lsum = 0.f;
#pragma unroll
            for (int j = 0; j < 16; ++j) { lg[j] = __expf(lg[j] - mx); lsum += lg[j]; }
            lsum += __shfl_xor(lsum, 16);
            lsum += __shfl_xor(lsum, 32);
            float itot = 1.0f / lsum;
            float sca  = itot * invn;    // fold invn into a' (GEMM2 x is raw)
#pragma unroll
            for (int j = 0; j < 16; ++j) asum_part[j] += lg[j] * itot;
#pragma unroll
            for (int kt = 0; kt < 4; ++kt) {
                aB[(16 * kt + 4 * quad + 0) * AS + sw] = (unsigned short)f2bf(lg[4 * kt + 0] * sca);
                aB[(16 * kt + 4 * quad + 1) * AS + sw] = (unsigned short)f2bf(lg[4 * kt + 1] * sca);
                aB[(16 * kt + 4 * quad + 2) * AS + sw] = (unsigned short)f2bf(lg[4 * kt + 2] * sca);
                aB[(16 * kt + 4 * quad + 3) * AS + sw] = (unsigned short)f2bf(lg[4 * kt + 3] * sca);
            }
        }
        __syncthreads();  // aB complete

        // ---- GEMM2: V[k=16w..][c] += a'[k][s] x X^T[s][c] ----
#pragma unroll
        for (int ks = 0; ks < 2; ++ks) {
            short8 af = *(const short8*)&aB[(16 * w + m) * AS + 32 * ks + 8 * quad];
#pragma unroll
            for (int nt = 0; nt < 8; ++nt) {
                short8 bf_ = *(const short8*)&xC[(16 * nt + m) * XCS + 32 * ks + 8 * quad];
                acc[nt] = __builtin_amdgcn_mfma_f32_16x16x32_bf16(af, bf_, acc[nt], 0, 0, 0);
            }
        }
    }

    // ---- commit vlad partials (16 chunk-blocks contend per address) ----
    float* vb = vlad + ((size_t)n * Kk + 16 * w + 4 * quad) * Cc + m;
#pragma unroll
    for (int nt = 0; nt < 8; ++nt) {
        atomicAdd(vb + 0 * Cc + 16 * nt, acc[nt].x);
        atomicAdd(vb + 1 * Cc + 16 * nt, acc[nt].y);
        atomicAdd(vb + 2 * Cc + 16 * nt, acc[nt].z);
        atomicAdd(vb + 3 * Cc + 16 * nt, acc[nt].w);
    }

    // ---- asum: in-wave reduce over s-lanes, cross-wave via LDS, one atomic/k ----
#pragma unroll
    for (int j = 0; j < 16; ++j) {
        float v = asum_part[j];
        v += __shfl_xor(v, 1);
        v += __shfl_xor(v, 2);
        v += __shfl_xor(v, 4);
        v += __shfl_xor(v, 8);
        asum_part[j] = v;
    }
    __syncthreads();  // red's last (invn) reads done; safe to alias
    if (m == 0) {
#pragma unroll
        for (int kt = 0; kt < 4; ++kt)
#pragma unroll
            for (int r = 0; r < 4; ++r)
                asumLDS[w * 64 + 16 * kt + 4 * quad + r] = asum_part[4 * kt + r];
    }
    __syncthreads();
    if (t < Kk) {
        float s_ = asumLDS[t] + asumLDS[64 + t] + asumLDS[128 + t] + asumLDS[192 + t];
        atomicAdd(&asum[n * Kk + t], s_);
    }
}

// Parallel finalize: one block per n. Phase 1: per-k intra-norm scale via
// 4-thread teams + LDS reduce. Phase 2: out[n][c] = sum_k scale*(vlad-as*cent).
__global__ __launch_bounds__(256) void netvlad_final(
    const float* __restrict__ vlad, const float* __restrict__ asum,
    const float* __restrict__ centroids, const float* __restrict__ fc_w,
    float* __restrict__ out)
{
    __shared__ float scale_s[Kk];
    __shared__ float asum_s[Kk];
    __shared__ float red2[Kk][4];

    const int n = blockIdx.x;
    const int t = threadIdx.x;
    const int k = t >> 2;
    const int q = t & 3;

    const float* vr = vlad + ((size_t)n * Kk + k) * Cc + q * 32;
    const float* cr = centroids + k * Cc + q * 32;
    const float  as = asum[n * Kk + k];

    float ssq = 0.f;
#pragma unroll
    for (int i = 0; i < 8; ++i) {
        float4 v4 = *(const float4*)(vr + 4 * i);
        float4 c4 = *(const float4*)(cr + 4 * i);
        float d0 = v4.x - as * c4.x;
        float d1 = v4.y - as * c4.y;
        float d2 = v4.z - as * c4.z;
        float d3 = v4.w - as * c4.w;
        ssq += d0 * d0 + d1 * d1 + d2 * d2 + d3 * d3;
    }
    red2[k][q] = ssq;
    __syncthreads();
    if (q == 0) {
        float tot = red2[k][0] + red2[k][1] + red2[k][2] + red2[k][3];
        scale_s[k] = fc_w[k] / fmaxf(sqrtf(tot), 1e-12f);
        asum_s[k]  = as;
    }
    __syncthreads();

    if (t < Cc) {
        const int c = t;
        const float* vbp = vlad + (size_t)n * Kk * Cc + c;
        float o = 0.f;
#pragma unroll 8
        for (int k2 = 0; k2 < Kk; ++k2)
            o += scale_s[k2] * (vbp[k2 * Cc] - asum_s[k2] * centroids[k2 * Cc + c]);
        out[n * Cc + c] = o;
    }
}

extern "C" void kernel_launch(void* const* d_in, const int* in_sizes, int n_in,
                              void* d_out, int out_size, void* d_ws, size_t ws_size,
                              hipStream_t stream) {
    (void)in_sizes; (void)n_in; (void)out_size; (void)ws_size;
    const float* x         = (const float*)d_in[0];
    const float* conv_w    = (const float*)d_in[1];
    const float* conv_b    = (const float*)d_in[2];
    const float* centroids = (const float*)d_in[3];
    const float* fc_w      = (const float*)d_in[4];
    float* out = (float*)d_out;

    float* vlad = (float*)d_ws;                         // [N][K][C] = 1 MB
    float* asum = vlad + (size_t)Nn * Kk * Cc;          // [N][K]    = 8 KB
    size_t zero_bytes = ((size_t)Nn * Kk * Cc + (size_t)Nn * Kk) * sizeof(float);
    hipMemsetAsync(d_ws, 0, zero_bytes, stream);        // ws is poisoned 0xAA each call

    dim3 grid(NCHUNK, Nn);
    netvlad_main<<<grid, BLK, 0, stream>>>(x, conv_w, conv_b, vlad, asum);
    netvlad_final<<<Nn, 256, 0, stream>>>(vlad, asum, centroids, fc_w, out);
}